// Round 1
// baseline (348.375 us; speedup 1.0000x reference)
//
#include <hip/hip_runtime.h>

#define NN 50000
#define KE 32

__device__ __forceinline__ void fma4(float4& acc, float s, const float4& w) {
    acc.x += s * w.x; acc.y += s * w.y; acc.z += s * w.z; acc.w += s * w.w;
}

// Kernel A: fold attn_vec through W_q / W_k.
// u[h][i] = sum_d W_q[i][h*32+d] * a_q[h][d];  v likewise from W_k, a_k.
__global__ __launch_bounds__(256) void fold_kernel(const float* __restrict__ Wq,
        const float* __restrict__ Wk, const float* __restrict__ av,
        float* __restrict__ u, float* __restrict__ v) {
    int t = blockIdx.x * blockDim.x + threadIdx.x;
    if (t >= 512) return;
    int h = t >> 7, i = t & 127;
    float su = 0.f, sv = 0.f;
#pragma unroll
    for (int d = 0; d < 32; ++d) {
        su += Wq[i * 128 + h * 32 + d] * av[h * 64 + d];
        sv += Wk[i * 128 + h * 32 + d] * av[h * 64 + 32 + d];
    }
    u[h * 128 + i] = su;
    v[h * 128 + i] = sv;
}

// Kernel B: V = concat(x, emb) @ W_v.  32 rows x 128 cols per block;
// each thread owns a 4-row x 4-col (float4) microtile.
__global__ __launch_bounds__(256) void vproj_kernel(const float* __restrict__ x,
        const float* __restrict__ emb, const float* __restrict__ Wv,
        float* __restrict__ V) {
    const int c = (threadIdx.x & 31) * 4;   // col 0..124 step 4
    const int rg = threadIdx.x >> 5;        // row group 0..7
    const int row0 = blockIdx.x * 32 + rg * 4;
    float4 acc[4];
#pragma unroll
    for (int i = 0; i < 4; ++i) acc[i] = make_float4(0.f, 0.f, 0.f, 0.f);
    const float* xp[4];
    const float* ep[4];
#pragma unroll
    for (int i = 0; i < 4; ++i) {
        int r = row0 + i; if (r > NN - 1) r = NN - 1;
        xp[i] = x + (long)r * 128;
        ep[i] = emb + (long)r * 128;
    }
    const float* wx = Wv + c;               // W rows 0..127 multiply x
    const float* we = Wv + 128 * 128 + c;   // W rows 128..255 multiply emb
    for (int k = 0; k < 128; k += 4) {
        float4 w0 = *(const float4*)(wx + (k + 0) * 128);
        float4 w1 = *(const float4*)(wx + (k + 1) * 128);
        float4 w2 = *(const float4*)(wx + (k + 2) * 128);
        float4 w3 = *(const float4*)(wx + (k + 3) * 128);
#pragma unroll
        for (int i = 0; i < 4; ++i) {
            float4 a = *(const float4*)(xp[i] + k);
            fma4(acc[i], a.x, w0); fma4(acc[i], a.y, w1);
            fma4(acc[i], a.z, w2); fma4(acc[i], a.w, w3);
        }
    }
    for (int k = 0; k < 128; k += 4) {
        float4 w0 = *(const float4*)(we + (k + 0) * 128);
        float4 w1 = *(const float4*)(we + (k + 1) * 128);
        float4 w2 = *(const float4*)(we + (k + 2) * 128);
        float4 w3 = *(const float4*)(we + (k + 3) * 128);
#pragma unroll
        for (int i = 0; i < 4; ++i) {
            float4 a = *(const float4*)(ep[i] + k);
            fma4(acc[i], a.x, w0); fma4(acc[i], a.y, w1);
            fma4(acc[i], a.z, w2); fma4(acc[i], a.w, w3);
        }
    }
#pragma unroll
    for (int i = 0; i < 4; ++i) {
        int r = row0 + i;
        if (r < NN) *(float4*)(V + (long)r * 128 + c) = acc[i];
    }
}

// Kernel D: sq[n][h] = emb[n]·u_h, sk[n][h] = emb[n]·v_h. One wave per node.
__global__ __launch_bounds__(256) void score_kernel(const float* __restrict__ emb,
        const float* __restrict__ u, const float* __restrict__ v,
        float* __restrict__ sq, float* __restrict__ sk) {
    const int w = threadIdx.x >> 6;
    const int lane = threadIdx.x & 63;
    const int n = blockIdx.x * 4 + w;            // grid*4 == NN exactly
    const float ea = emb[(long)n * 128 + lane];
    const float eb = emb[(long)n * 128 + 64 + lane];
    float q[4], k_[4];
#pragma unroll
    for (int h = 0; h < 4; ++h) {
        float pu = ea * u[h * 128 + lane] + eb * u[h * 128 + 64 + lane];
        float pv = ea * v[h * 128 + lane] + eb * v[h * 128 + 64 + lane];
#pragma unroll
        for (int off = 32; off > 0; off >>= 1) {
            pu += __shfl_xor(pu, off);
            pv += __shfl_xor(pv, off);
        }
        q[h] = pu; k_[h] = pv;
    }
    if (lane == 0) {
        *(float4*)(sq + (long)n * 4) = make_float4(q[0], q[1], q[2], q[3]);
        *(float4*)(sk + (long)n * 4) = make_float4(k_[0], k_[1], k_[2], k_[3]);
    }
}

// Kernel C: per-node attention softmax + weighted gather + ELU + LayerNorm.
// One wave per node; 4 nodes per 256-thread block.
__global__ __launch_bounds__(256) void aggregate_kernel(const int* __restrict__ src,
        const float* __restrict__ sq, const float* __restrict__ sk,
        const float* __restrict__ V, const float* __restrict__ gamma,
        const float* __restrict__ beta, float* __restrict__ out) {
    __shared__ int s_src[4][32];
    __shared__ float4 s_alpha[4][32];
    const int w = threadIdx.x >> 6;
    const int lane = threadIdx.x & 63;
    const int n = blockIdx.x * 4 + w;            // grid*4 == NN exactly

    if (lane < 32) {
        const int s = src[(long)n * KE + lane];
        float4 sk4 = *(const float4*)(sk + (long)s * 4);
        float4 sq4 = *(const float4*)(sq + (long)n * 4);
        float e[4] = { sq4.x + sk4.x, sq4.y + sk4.y, sq4.z + sk4.z, sq4.w + sk4.w };
#pragma unroll
        for (int h = 0; h < 4; ++h) e[h] = e[h] > 0.f ? e[h] : 0.2f * e[h];
        float m[4] = { e[0], e[1], e[2], e[3] };
#pragma unroll
        for (int off = 16; off > 0; off >>= 1) {
#pragma unroll
            for (int h = 0; h < 4; ++h) m[h] = fmaxf(m[h], __shfl_xor(m[h], off));
        }
        float ex[4], sum[4];
#pragma unroll
        for (int h = 0; h < 4; ++h) { ex[h] = __expf(e[h] - m[h]); sum[h] = ex[h]; }
#pragma unroll
        for (int off = 16; off > 0; off >>= 1) {
#pragma unroll
            for (int h = 0; h < 4; ++h) sum[h] += __shfl_xor(sum[h], off);
        }
        float4 al;
        al.x = ex[0] / (sum[0] + 1e-8f);
        al.y = ex[1] / (sum[1] + 1e-8f);
        al.z = ex[2] / (sum[2] + 1e-8f);
        al.w = ex[3] / (sum[3] + 1e-8f);
        s_src[w][lane] = s;
        s_alpha[w][lane] = al;
    }
    __syncthreads();

    const int c0 = lane * 2;
    const int h = lane >> 4;       // component c0 = 2*lane -> head (2*lane)/32
    float zx = 0.f, zy = 0.f;
#pragma unroll 8
    for (int e = 0; e < 32; ++e) {
        const int s = s_src[w][e];
        const float a = ((const float*)&s_alpha[w][e])[h];
        float2 v2 = *(const float2*)(V + (long)s * 128 + c0);
        zx += a * v2.x;
        zy += a * v2.y;
    }
    // ELU
    zx = zx > 0.f ? zx : __expf(zx) - 1.f;
    zy = zy > 0.f ? zy : __expf(zy) - 1.f;
    // LayerNorm over 128 components (wave reduction)
    float s1 = zx + zy;
    float s2 = zx * zx + zy * zy;
#pragma unroll
    for (int off = 32; off > 0; off >>= 1) {
        s1 += __shfl_xor(s1, off);
        s2 += __shfl_xor(s2, off);
    }
    const float mu = s1 * (1.f / 128.f);
    const float var = s2 * (1.f / 128.f) - mu * mu;
    const float rstd = rsqrtf(var + 1e-5f);
    float2 g = *(const float2*)(gamma + c0);
    float2 b = *(const float2*)(beta + c0);
    float2 o;
    o.x = (zx - mu) * rstd * g.x + b.x;
    o.y = (zy - mu) * rstd * g.y + b.y;
    *(float2*)(out + (long)n * 128 + c0) = o;
}

extern "C" void kernel_launch(void* const* d_in, const int* in_sizes, int n_in,
                              void* d_out, int out_size, void* d_ws, size_t ws_size,
                              hipStream_t stream) {
    const float* x     = (const float*)d_in[0];
    const float* emb   = (const float*)d_in[1];
    const int*   edge  = (const int*)d_in[2];   // [0:E] = src, [E:2E] = dst (implicit)
    const float* Wq    = (const float*)d_in[3];
    const float* Wk    = (const float*)d_in[4];
    const float* Wv    = (const float*)d_in[5];
    const float* av    = (const float*)d_in[6];
    const float* gamma = (const float*)d_in[7];
    const float* beta  = (const float*)d_in[8];
    float* out = (float*)d_out;

    float* ws = (float*)d_ws;
    float* u  = ws;                 // 512 floats
    float* v  = ws + 512;           // 512 floats
    float* sq = ws + 1024;          // 200000 floats
    float* sk = sq + 200000;        // 200000 floats
    float* V  = sk + 200000;        // 6.4M floats

    fold_kernel<<<2, 256, 0, stream>>>(Wq, Wk, av, u, v);
    vproj_kernel<<<(NN + 31) / 32, 256, 0, stream>>>(x, emb, Wv, V);
    score_kernel<<<NN / 4, 256, 0, stream>>>(emb, u, v, sq, sk);
    aggregate_kernel<<<NN / 4, 256, 0, stream>>>(edge, sq, sk, V, gamma, beta, out);
}

// Round 2
// 196.971 us; speedup vs baseline: 1.7687x; 1.7687x over previous
//
#include <hip/hip_runtime.h>

#define NN 50000
#define KE 32

using f32x4  = __attribute__((ext_vector_type(4))) float;
using bf16x8 = __attribute__((ext_vector_type(8))) short;

__device__ __forceinline__ ushort f2bf(float f) {
    union { float f; unsigned u; } c; c.f = f;
    unsigned u = c.u;
    u += 0x7fffu + ((u >> 16) & 1u);        // round-to-nearest-even
    return (ushort)(u >> 16);
}

// Kernel A: fold attn_vec through W_q / W_k  (blocks 0-1), and cast W_v into
// Bt[n][k] = bf16(W_v[k][n])  (blocks 2..129).
__global__ __launch_bounds__(256) void prep_kernel(const float* __restrict__ Wq,
        const float* __restrict__ Wk, const float* __restrict__ av,
        const float* __restrict__ Wv, float* __restrict__ u, float* __restrict__ v,
        ushort* __restrict__ Bt) {
    const int g = blockIdx.x * 256 + threadIdx.x;
    if (blockIdx.x < 2) {
        const int h = g >> 7, i = g & 127;
        float su = 0.f, sv = 0.f;
#pragma unroll
        for (int d = 0; d < 32; ++d) {
            su += Wq[i * 128 + h * 32 + d] * av[h * 64 + d];
            sv += Wk[i * 128 + h * 32 + d] * av[h * 64 + 32 + d];
        }
        u[h * 128 + i] = su;
        v[h * 128 + i] = sv;
    } else {
        const int idx = g - 512;            // 0..32767, coalesced read of Wv
        const int k = idx >> 7, n = idx & 127;
        Bt[n * 256 + k] = f2bf(Wv[idx]);
    }
}

// Kernel B: V = concat(x, emb) @ W_v via bf16 MFMA. Block tile 64 rows x 128
// cols; 4 waves, each owns 32 cols x 64 rows. A staged in LDS (bf16, row
// stride 264 = 256+8 pad -> 2-way bank aliasing only, free). B frags from
// global (Bt is 64 KB, L1/L2-hot). V stored bf16.
__global__ __launch_bounds__(256) void vproj_mfma(const float* __restrict__ x,
        const float* __restrict__ emb, const ushort* __restrict__ Bt,
        ushort* __restrict__ Vb) {
    __shared__ short As[64 * 264];
    const int t = threadIdx.x;
    const int rbase = blockIdx.x * 64;

    // ---- stage A: 64 rows x 256 k, fp32 -> bf16 ----
#pragma unroll
    for (int it = 0; it < 16; ++it) {
        const int li = it * 256 + t;        // 0..4095 float4-slots
        const int row = li >> 6;            // 0..63
        const int c4 = li & 63;             // float4 index within 256-wide row
        int rg = rbase + row; if (rg >= NN) rg = NN - 1;
        const float* sp = (c4 < 32) ? (x + (long)rg * 128 + c4 * 4)
                                    : (emb + (long)rg * 128 + (c4 - 32) * 4);
        float4 a = *(const float4*)sp;
        ushort4 b = make_ushort4(f2bf(a.x), f2bf(a.y), f2bf(a.z), f2bf(a.w));
        *(ushort4*)&As[row * 264 + c4 * 4] = b;
    }
    __syncthreads();

    const int wv = t >> 6;
    const int lane = t & 63;
    const int lo = lane & 15;
    const int quad = lane >> 4;
    const int c0 = wv * 32;

    f32x4 acc[4][2] = {};
    for (int ks = 0; ks < 8; ++ks) {
        const int kb = ks * 32 + quad * 8;
        bf16x8 bf0 = *(const bf16x8*)(Bt + (c0 + lo) * 256 + kb);
        bf16x8 bf1 = *(const bf16x8*)(Bt + (c0 + 16 + lo) * 256 + kb);
#pragma unroll
        for (int rt = 0; rt < 4; ++rt) {
            bf16x8 af = *(const bf16x8*)&As[(rt * 16 + lo) * 264 + kb];
            acc[rt][0] = __builtin_amdgcn_mfma_f32_16x16x32_bf16(af, bf0, acc[rt][0], 0, 0, 0);
            acc[rt][1] = __builtin_amdgcn_mfma_f32_16x16x32_bf16(af, bf1, acc[rt][1], 0, 0, 0);
        }
    }
    // ---- epilogue: C/D layout col=lane&15, row=quad*4+reg ----
#pragma unroll
    for (int rt = 0; rt < 4; ++rt) {
#pragma unroll
        for (int ct = 0; ct < 2; ++ct) {
#pragma unroll
            for (int r = 0; r < 4; ++r) {
                const int row = rbase + rt * 16 + quad * 4 + r;
                if (row < NN)
                    Vb[(long)row * 128 + c0 + ct * 16 + lo] = f2bf(acc[rt][ct][r]);
            }
        }
    }
}

// Kernel C: sq[n][h] = emb[n]·u_h, sk[n][h] = emb[n]·v_h. One wave per node.
__global__ __launch_bounds__(256) void score_kernel(const float* __restrict__ emb,
        const float* __restrict__ u, const float* __restrict__ v,
        float* __restrict__ sq, float* __restrict__ sk) {
    const int w = threadIdx.x >> 6;
    const int lane = threadIdx.x & 63;
    const int n = blockIdx.x * 4 + w;
    const float ea = emb[(long)n * 128 + lane];
    const float eb = emb[(long)n * 128 + 64 + lane];
    float q[4], k_[4];
#pragma unroll
    for (int h = 0; h < 4; ++h) {
        float pu = ea * u[h * 128 + lane] + eb * u[h * 128 + 64 + lane];
        float pv = ea * v[h * 128 + lane] + eb * v[h * 128 + 64 + lane];
#pragma unroll
        for (int off = 32; off > 0; off >>= 1) {
            pu += __shfl_xor(pu, off);
            pv += __shfl_xor(pv, off);
        }
        q[h] = pu; k_[h] = pv;
    }
    if (lane == 0) {
        *(float4*)(sq + (long)n * 4) = make_float4(q[0], q[1], q[2], q[3]);
        *(float4*)(sk + (long)n * 4) = make_float4(k_[0], k_[1], k_[2], k_[3]);
    }
}

// Kernel D: per-node softmax + weighted gather (bf16 V) + ELU + LayerNorm.
__global__ __launch_bounds__(256) void aggregate_kernel(const int* __restrict__ src,
        const float* __restrict__ sq, const float* __restrict__ sk,
        const ushort* __restrict__ Vb, const float* __restrict__ gamma,
        const float* __restrict__ beta, float* __restrict__ out) {
    __shared__ int s_src[4][32];
    __shared__ float4 s_alpha[4][32];
    const int w = threadIdx.x >> 6;
    const int lane = threadIdx.x & 63;
    const int n = blockIdx.x * 4 + w;

    if (lane < 32) {
        const int s = src[(long)n * KE + lane];
        float4 sk4 = *(const float4*)(sk + (long)s * 4);
        float4 sq4 = *(const float4*)(sq + (long)n * 4);
        float e[4] = { sq4.x + sk4.x, sq4.y + sk4.y, sq4.z + sk4.z, sq4.w + sk4.w };
#pragma unroll
        for (int h = 0; h < 4; ++h) e[h] = e[h] > 0.f ? e[h] : 0.2f * e[h];
        float m[4] = { e[0], e[1], e[2], e[3] };
#pragma unroll
        for (int off = 16; off > 0; off >>= 1) {
#pragma unroll
            for (int h = 0; h < 4; ++h) m[h] = fmaxf(m[h], __shfl_xor(m[h], off));
        }
        float ex[4], sum[4];
#pragma unroll
        for (int h = 0; h < 4; ++h) { ex[h] = __expf(e[h] - m[h]); sum[h] = ex[h]; }
#pragma unroll
        for (int off = 16; off > 0; off >>= 1) {
#pragma unroll
            for (int h = 0; h < 4; ++h) sum[h] += __shfl_xor(sum[h], off);
        }
        float4 al;
        al.x = ex[0] / (sum[0] + 1e-8f);
        al.y = ex[1] / (sum[1] + 1e-8f);
        al.z = ex[2] / (sum[2] + 1e-8f);
        al.w = ex[3] / (sum[3] + 1e-8f);
        s_src[w][lane] = s;
        s_alpha[w][lane] = al;
    }
    __syncthreads();

    const int c0 = lane * 2;
    const int h = lane >> 4;
    float zx = 0.f, zy = 0.f;
#pragma unroll 8
    for (int e = 0; e < 32; ++e) {
        const int s = s_src[w][e];
        const float a = ((const float*)&s_alpha[w][e])[h];
        const unsigned p = *(const unsigned*)(Vb + (long)s * 128 + c0);
        union { unsigned u; float f; } vx, vy;
        vx.u = p << 16;
        vy.u = p & 0xffff0000u;
        zx += a * vx.f;
        zy += a * vy.f;
    }
    zx = zx > 0.f ? zx : __expf(zx) - 1.f;
    zy = zy > 0.f ? zy : __expf(zy) - 1.f;
    float s1 = zx + zy;
    float s2 = zx * zx + zy * zy;
#pragma unroll
    for (int off = 32; off > 0; off >>= 1) {
        s1 += __shfl_xor(s1, off);
        s2 += __shfl_xor(s2, off);
    }
    const float mu = s1 * (1.f / 128.f);
    const float var = s2 * (1.f / 128.f) - mu * mu;
    const float rstd = rsqrtf(var + 1e-5f);
    float2 g = *(const float2*)(gamma + c0);
    float2 b = *(const float2*)(beta + c0);
    float2 o;
    o.x = (zx - mu) * rstd * g.x + b.x;
    o.y = (zy - mu) * rstd * g.y + b.y;
    *(float2*)(out + (long)n * 128 + c0) = o;
}

extern "C" void kernel_launch(void* const* d_in, const int* in_sizes, int n_in,
                              void* d_out, int out_size, void* d_ws, size_t ws_size,
                              hipStream_t stream) {
    const float* x     = (const float*)d_in[0];
    const float* emb   = (const float*)d_in[1];
    const int*   edge  = (const int*)d_in[2];
    const float* Wq    = (const float*)d_in[3];
    const float* Wk    = (const float*)d_in[4];
    const float* Wv    = (const float*)d_in[5];
    const float* av    = (const float*)d_in[6];
    const float* gamma = (const float*)d_in[7];
    const float* beta  = (const float*)d_in[8];
    float* out = (float*)d_out;

    char* ws = (char*)d_ws;
    float*  u  = (float*)(ws + 0);              //   2048 B
    float*  v  = (float*)(ws + 2048);           //   2048 B
    float*  sq = (float*)(ws + 4096);           // 800000 B
    float*  sk = (float*)(ws + 804096);         // 800000 B
    ushort* Bt = (ushort*)(ws + 1604096);       //  65536 B (16-aligned)
    ushort* Vb = (ushort*)(ws + 1669632);       // 12.8 MB (16-aligned)

    prep_kernel<<<130, 256, 0, stream>>>(Wq, Wk, av, Wv, u, v, Bt);
    vproj_mfma<<<(NN + 63) / 64, 256, 0, stream>>>(x, emb, Bt, Vb);
    score_kernel<<<NN / 4, 256, 0, stream>>>(emb, u, v, sq, sk);
    aggregate_kernel<<<NN / 4, 256, 0, stream>>>(edge, sq, sk, Vb, gamma, beta, out);
}

// Round 3
// 178.161 us; speedup vs baseline: 1.9554x; 1.1056x over previous
//
#include <hip/hip_runtime.h>

#define NN 50000
#define KE 32

using f32x4  = __attribute__((ext_vector_type(4))) float;
using bf16x8 = __attribute__((ext_vector_type(8))) short;

__device__ __forceinline__ ushort f2bf(float f) {
    union { float f; unsigned u; } c; c.f = f;
    unsigned u = c.u;
    u += 0x7fffu + ((u >> 16) & 1u);        // round-to-nearest-even
    return (ushort)(u >> 16);
}

// Kernel A (blocks 0-1): fold attn_vec through W_q/W_k into bf16 Ub[16][128]
// (cols 0-3 = u_h, 4-7 = v_h, rows 8-15 zeroed for MFMA B-operand).
// Blocks 2..129: cast W_v into Bt[n][k] = bf16(W_v[k][n]).
__global__ __launch_bounds__(256) void prep_kernel(const float* __restrict__ Wq,
        const float* __restrict__ Wk, const float* __restrict__ av,
        const float* __restrict__ Wv, ushort* __restrict__ Ub,
        ushort* __restrict__ Bt) {
    const int g = blockIdx.x * 256 + threadIdx.x;
    if (blockIdx.x < 2) {
        const int h = g >> 7, i = g & 127;
        float su = 0.f, sv = 0.f;
#pragma unroll
        for (int d = 0; d < 32; ++d) {
            su += Wq[i * 128 + h * 32 + d] * av[h * 64 + d];
            sv += Wk[i * 128 + h * 32 + d] * av[h * 64 + 32 + d];
        }
        Ub[h * 128 + i] = f2bf(su);
        Ub[(4 + h) * 128 + i] = f2bf(sv);
        Ub[1024 + g * 2] = 0;               // zero rows 8..15
        Ub[1024 + g * 2 + 1] = 0;
    } else {
        const int idx = g - 512;            // 0..32767, coalesced read of Wv
        const int k = idx >> 7, n = idx & 127;
        Bt[n * 256 + k] = f2bf(Wv[idx]);
    }
}

// Kernel B: V = concat(x, emb) @ W_v via bf16 MFMA (64 rows x 128 cols per
// block, 4 waves). Also computes sq/sk for the block's rows with 4 extra
// MFMAs per wave against Ub (emb half of the staged A tile). Epilogue
// round-trips through LDS for coalesced dwordx4 stores of bf16 V.
__global__ __launch_bounds__(256) void vproj_mfma(const float* __restrict__ x,
        const float* __restrict__ emb, const ushort* __restrict__ Bt,
        const ushort* __restrict__ Ub, float* __restrict__ sq,
        float* __restrict__ sk, ushort* __restrict__ Vb) {
    __shared__ short As[64 * 264];          // 33.8 KB; reused (stride 132) for epilogue
    const int t = threadIdx.x;
    const int rbase = blockIdx.x * 64;

    // ---- stage A: 64 rows x 256 k, fp32 -> bf16 ----
#pragma unroll
    for (int it = 0; it < 16; ++it) {
        const int li = it * 256 + t;        // float4-slot index
        const int row = li >> 6;
        const int c4 = li & 63;
        int rg = rbase + row; if (rg >= NN) rg = NN - 1;
        const float* sp = (c4 < 32) ? (x + (long)rg * 128 + c4 * 4)
                                    : (emb + (long)rg * 128 + (c4 - 32) * 4);
        float4 a = *(const float4*)sp;
        ushort4 b = make_ushort4(f2bf(a.x), f2bf(a.y), f2bf(a.z), f2bf(a.w));
        *(ushort4*)&As[row * 264 + c4 * 4] = b;
    }
    __syncthreads();

    const int wv = t >> 6;
    const int lane = t & 63;
    const int lo = lane & 15;
    const int quad = lane >> 4;
    const int c0 = wv * 32;

    f32x4 acc[4][2] = {};
    for (int ks = 0; ks < 8; ++ks) {
        const int kb = ks * 32 + quad * 8;
        bf16x8 bf0 = *(const bf16x8*)(Bt + (c0 + lo) * 256 + kb);
        bf16x8 bf1 = *(const bf16x8*)(Bt + (c0 + 16 + lo) * 256 + kb);
#pragma unroll
        for (int rt = 0; rt < 4; ++rt) {
            bf16x8 af = *(const bf16x8*)&As[(rt * 16 + lo) * 264 + kb];
            acc[rt][0] = __builtin_amdgcn_mfma_f32_16x16x32_bf16(af, bf0, acc[rt][0], 0, 0, 0);
            acc[rt][1] = __builtin_amdgcn_mfma_f32_16x16x32_bf16(af, bf1, acc[rt][1], 0, 0, 0);
        }
    }

    // ---- scores: wave wv handles rows wv*16..+15; K = emb dims (As cols 128+) ----
    f32x4 sacc = {};
#pragma unroll
    for (int ks = 0; ks < 4; ++ks) {
        const int kk = ks * 32 + quad * 8;
        bf16x8 saf = *(const bf16x8*)&As[(wv * 16 + lo) * 264 + 128 + kk];
        bf16x8 sbf = *(const bf16x8*)(Ub + lo * 128 + kk);
        sacc = __builtin_amdgcn_mfma_f32_16x16x32_bf16(saf, sbf, sacc, 0, 0, 0);
    }
    if (lo < 8) {
#pragma unroll
        for (int r = 0; r < 4; ++r) {
            const int row = rbase + wv * 16 + quad * 4 + r;
            if (row < NN) {
                if (lo < 4) sq[(long)row * 4 + lo] = sacc[r];
                else        sk[(long)row * 4 + lo - 4] = sacc[r];
            }
        }
    }

    // ---- epilogue: regs -> LDS (bf16, stride 132) -> coalesced global ----
    __syncthreads();                        // all As reads done
#pragma unroll
    for (int rt = 0; rt < 4; ++rt)
#pragma unroll
        for (int ct = 0; ct < 2; ++ct)
#pragma unroll
            for (int r = 0; r < 4; ++r)
                As[(rt * 16 + quad * 4 + r) * 132 + c0 + ct * 16 + lo] =
                    (short)f2bf(acc[rt][ct][r]);
    __syncthreads();
#pragma unroll
    for (int i = 0; i < 4; ++i) {
        const int idx = i * 256 + t;
        const int row = idx >> 4;
        const int seg = idx & 15;
        const int grow = rbase + row;
        if (grow < NN)
            *(bf16x8*)(Vb + (long)grow * 128 + seg * 8) =
                *(const bf16x8*)&As[row * 132 + seg * 8];
    }
}

// Kernel C: per-node softmax + vectorized weighted gather (bf16 V, dwordx4
// per lane, 4 edges per wave-iteration) + ELU + LayerNorm.
__global__ __launch_bounds__(256) void aggregate_kernel(const int* __restrict__ src,
        const float* __restrict__ sq, const float* __restrict__ sk,
        const ushort* __restrict__ Vb, const float* __restrict__ gamma,
        const float* __restrict__ beta, float* __restrict__ out) {
    __shared__ int s_src[4][32];
    __shared__ float4 s_alpha[4][32];
    const int w = threadIdx.x >> 6;
    const int lane = threadIdx.x & 63;
    const int n = blockIdx.x * 4 + w;

    if (lane < 32) {
        const int s = src[(long)n * KE + lane];
        float4 sk4 = *(const float4*)(sk + (long)s * 4);
        float4 sq4 = *(const float4*)(sq + (long)n * 4);
        float e[4] = { sq4.x + sk4.x, sq4.y + sk4.y, sq4.z + sk4.z, sq4.w + sk4.w };
#pragma unroll
        for (int h = 0; h < 4; ++h) e[h] = e[h] > 0.f ? e[h] : 0.2f * e[h];
        float m[4] = { e[0], e[1], e[2], e[3] };
#pragma unroll
        for (int off = 16; off > 0; off >>= 1) {
#pragma unroll
            for (int h = 0; h < 4; ++h) m[h] = fmaxf(m[h], __shfl_xor(m[h], off));
        }
        float ex[4], sum[4];
#pragma unroll
        for (int h = 0; h < 4; ++h) { ex[h] = __expf(e[h] - m[h]); sum[h] = ex[h]; }
#pragma unroll
        for (int off = 16; off > 0; off >>= 1) {
#pragma unroll
            for (int h = 0; h < 4; ++h) sum[h] += __shfl_xor(sum[h], off);
        }
        float4 al;
        al.x = ex[0] / (sum[0] + 1e-8f);
        al.y = ex[1] / (sum[1] + 1e-8f);
        al.z = ex[2] / (sum[2] + 1e-8f);
        al.w = ex[3] / (sum[3] + 1e-8f);
        s_src[w][lane] = s;
        s_alpha[w][lane] = al;
    }
    __syncthreads();

    const int g  = lane >> 4;      // edge subgroup 0..3
    const int li = lane & 15;      // column group: cols li*8 .. li*8+7
    const int h  = li >> 2;        // head of these 8 cols
    float z[8] = {};
#pragma unroll
    for (int it = 0; it < 8; ++it) {
        const int e = it * 4 + g;
        const int s = s_src[w][e];
        const float a = ((const float*)&s_alpha[w][e])[h];
        uint4 p = *(const uint4*)(Vb + (long)s * 128 + li * 8);
        const unsigned pc[4] = { p.x, p.y, p.z, p.w };
#pragma unroll
        for (int j = 0; j < 4; ++j) {
            union { unsigned u; float f; } ve, vo;
            ve.u = pc[j] << 16;
            vo.u = pc[j] & 0xffff0000u;
            z[2 * j]     += a * ve.f;
            z[2 * j + 1] += a * vo.f;
        }
    }
    // sum over the 4 edge subgroups (lanes differing in bits 4-5)
#pragma unroll
    for (int j = 0; j < 8; ++j) {
        z[j] += __shfl_xor(z[j], 16);
        z[j] += __shfl_xor(z[j], 32);
    }
    // ELU (replicated across subgroups — consistent)
    float s1 = 0.f, s2 = 0.f;
#pragma unroll
    for (int j = 0; j < 8; ++j) {
        z[j] = z[j] > 0.f ? z[j] : __expf(z[j]) - 1.f;
        s1 += z[j];
        s2 += z[j] * z[j];
    }
    // LayerNorm sums over the 16 column groups
#pragma unroll
    for (int off = 8; off > 0; off >>= 1) {
        s1 += __shfl_xor(s1, off);
        s2 += __shfl_xor(s2, off);
    }
    const float mu = s1 * (1.f / 128.f);
    const float var = s2 * (1.f / 128.f) - mu * mu;
    const float rstd = rsqrtf(var + 1e-5f);
    if (g < 2) {
        const int c0 = li * 8 + g * 4;
        float4 ga = *(const float4*)(gamma + c0);
        float4 be = *(const float4*)(beta + c0);
        float4 o;
        o.x = (z[g * 4 + 0] - mu) * rstd * ga.x + be.x;
        o.y = (z[g * 4 + 1] - mu) * rstd * ga.y + be.y;
        o.z = (z[g * 4 + 2] - mu) * rstd * ga.z + be.z;
        o.w = (z[g * 4 + 3] - mu) * rstd * ga.w + be.w;
        *(float4*)(out + (long)n * 128 + c0) = o;
    }
}

extern "C" void kernel_launch(void* const* d_in, const int* in_sizes, int n_in,
                              void* d_out, int out_size, void* d_ws, size_t ws_size,
                              hipStream_t stream) {
    const float* x     = (const float*)d_in[0];
    const float* emb   = (const float*)d_in[1];
    const int*   edge  = (const int*)d_in[2];
    const float* Wq    = (const float*)d_in[3];
    const float* Wk    = (const float*)d_in[4];
    const float* Wv    = (const float*)d_in[5];
    const float* av    = (const float*)d_in[6];
    const float* gamma = (const float*)d_in[7];
    const float* beta  = (const float*)d_in[8];
    float* out = (float*)d_out;

    char* ws = (char*)d_ws;
    ushort* Ub = (ushort*)(ws + 0);             //   4096 B (16x128 bf16)
    ushort* Bt = (ushort*)(ws + 4096);          //  65536 B
    float*  sq = (float*)(ws + 69632);          // 800000 B
    float*  sk = (float*)(ws + 869632);         // 800000 B
    ushort* Vb = (ushort*)(ws + 1669632);       // 12.8 MB

    prep_kernel<<<130, 256, 0, stream>>>(Wq, Wk, av, Wv, Ub, Bt);
    vproj_mfma<<<(NN + 63) / 64, 256, 0, stream>>>(x, emb, Bt, Ub, sq, sk, Vb);
    aggregate_kernel<<<NN / 4, 256, 0, stream>>>(edge, sq, sk, Vb, gamma, beta, out);
}